// Round 4
// baseline (284.960 us; speedup 1.0000x reference)
//
#include <hip/hip_runtime.h>
#include <hip/hip_bf16.h>
#include <stdint.h>

#define N 8192
#define D 512
#define TILE 128
#define NKB (D / 32)                  // 16 k-chunks of 32
#define NTB (N / TILE)                // 64 tile-rows
#define NBLK (NTB * (NTB + 1) / 2)    // 2080 upper-tri blocks

typedef __attribute__((ext_vector_type(8))) short bf16x8;
typedef __attribute__((ext_vector_type(4))) float f32x4;

__device__ __forceinline__ short f2bf(float x) {
    uint32_t u = __float_as_uint(x);
    u += 0x7fffu + ((u >> 16) & 1u);   // RNE; inputs finite/small
    return (short)(u >> 16);
}

// Fn2 fragment-major layout: [rb 0..511][kb 0..15][lane 0..63][8 bf16]
// lane l of (rb,kb) holds row rb*16+(l&15), k = kb*32+(l>>4)*8 .. +7
// -> an MFMA A/B fragment load is 64 lanes x contiguous 16B = 1KB coalesced.

// one wave per row: fp32 row -> L2-normalized bf16 fragment-major.
// Blocks 0..15 zero tot/pos; block 16 zeroes the done-counter.
__global__ void cc_normalize(const float* __restrict__ F, short* __restrict__ Fn2,
                             float* __restrict__ totpos, int* __restrict__ cnt) {
    if (blockIdx.x < 16)
        ((float4*)totpos)[blockIdx.x * 256 + threadIdx.x] = make_float4(0.f, 0.f, 0.f, 0.f);
    if (blockIdx.x == 16 && threadIdx.x == 0) *cnt = 0;

    const int row  = blockIdx.x * 4 + (threadIdx.x >> 6);
    const int lane = threadIdx.x & 63;
    const float* p = F + (size_t)row * D + lane * 8;   // 8 consecutive elems/lane
    float4 a = *(const float4*)p;
    float4 b = *(const float4*)(p + 4);
    float ss = a.x*a.x + a.y*a.y + a.z*a.z + a.w*a.w
             + b.x*b.x + b.y*b.y + b.z*b.z + b.w*b.w;
    #pragma unroll
    for (int m = 32; m; m >>= 1) ss += __shfl_xor(ss, m, 64);
    const float inv = 1.0f / fmaxf(sqrtf(ss), 1e-12f);
    bf16x8 o;
    o[0] = f2bf(a.x*inv); o[1] = f2bf(a.y*inv); o[2] = f2bf(a.z*inv); o[3] = f2bf(a.w*inv);
    o[4] = f2bf(b.x*inv); o[5] = f2bf(b.y*inv); o[6] = f2bf(b.z*inv); o[7] = f2bf(b.w*inv);
    // kb = lane>>2, q = lane&3, fragment lane = q*16 + (row&15)
    const size_t idx = ((size_t)(row >> 4) * NKB + (lane >> 2)) * 64
                     + (lane & 3) * 16 + (row & 15);
    *(bf16x8*)(Fn2 + idx * 8) = o;
}

// Upper-tri tiles, barrier-free K-loop: fragments straight from global (L2-hot).
// exp -> masked row sums (+ col sums for off-diag, by symmetry) -> atomics.
// Last block to finish runs the finalize reduction.
__global__ __launch_bounds__(256, 3)
void cc_gemm(const short* __restrict__ Fn2, const int* __restrict__ cl,
             float* __restrict__ tot, float* __restrict__ pos,
             int* __restrict__ cnt, float* __restrict__ out) {
    __shared__ int crow[TILE], ccol[TILE];
    __shared__ float red[4];
    __shared__ int lastflag;

    const int tid  = threadIdx.x;
    const int wave = tid >> 6;
    const int lane = tid & 63;

    // decode upper-triangle block index -> (bm, bn), bm <= bn
    int rem = blockIdx.x, bm = 0;
    while (rem >= NTB - bm) { rem -= NTB - bm; ++bm; }
    const int bn = bm + rem;
    const bool diag = (bm == bn);

    if (tid < TILE)            crow[tid]        = cl[bm * TILE + tid];
    else                       ccol[tid - TILE] = cl[bn * TILE + (tid - TILE)];

    const int wr = wave >> 1, wc = wave & 1;    // 2x2 wave grid, 64x64 each
    const int q   = lane >> 4;
    const int n15 = lane & 15;

    f32x4 acc[4][4];
    #pragma unroll
    for (int t = 0; t < 4; ++t)
        #pragma unroll
        for (int u = 0; u < 4; ++u) acc[t][u] = (f32x4)(0.0f);

    // per-fragment base pointers (advance 512 elems per kb)
    const short* pa[4];
    const short* pb[4];
    #pragma unroll
    for (int t = 0; t < 4; ++t)
        pa[t] = Fn2 + ((size_t)(bm * 8 + wr * 4 + t) * NKB * 64 + lane) * 8;
    #pragma unroll
    for (int u = 0; u < 4; ++u)
        pb[u] = Fn2 + ((size_t)(bn * 8 + wc * 4 + u) * NKB * 64 + lane) * 8;

    __syncthreads();   // crow/ccol ready (only barrier before epilogue)

    #pragma unroll 2
    for (int kb = 0; kb < NKB; ++kb) {
        bf16x8 af[4], bfr[4];
        #pragma unroll
        for (int t = 0; t < 4; ++t) af[t]  = *(const bf16x8*)(pa[t] + (size_t)kb * 512);
        #pragma unroll
        for (int u = 0; u < 4; ++u) bfr[u] = *(const bf16x8*)(pb[u] + (size_t)kb * 512);
        #pragma unroll
        for (int t = 0; t < 4; ++t)
            #pragma unroll
            for (int u = 0; u < 4; ++u)
                acc[t][u] = __builtin_amdgcn_mfma_f32_16x16x32_bf16(af[t], bfr[u], acc[t][u], 0, 0, 0);
    }

    // epilogue: e = exp(sim/T) = exp2(dot * 10*log2(e)); C layout col=lane&15, row=q*4+reg
    const float SC = 14.426950408889634f;
    int cc[4];
    #pragma unroll
    for (int u = 0; u < 4; ++u) cc[u] = ccol[wc * 64 + u * 16 + n15];

    float ce[4] = {0.f, 0.f, 0.f, 0.f};   // per-column (lane-local) sums
    float cp[4] = {0.f, 0.f, 0.f, 0.f};

    #pragma unroll
    for (int t = 0; t < 4; ++t) {
        #pragma unroll
        for (int r = 0; r < 4; ++r) {
            const int lr  = wr * 64 + t * 16 + q * 4 + r;   // local row
            const int myc = crow[lr];
            float te = 0.0f, tp = 0.0f;
            #pragma unroll
            for (int u = 0; u < 4; ++u) {
                const float e  = exp2f(acc[t][u][r] * SC);
                const float ep = (cc[u] == myc) ? e : 0.0f;
                te += e;  tp += ep;
                ce[u] += e;  cp[u] += ep;
            }
            #pragma unroll
            for (int m = 1; m < 16; m <<= 1) {   // reduce across 16 cols
                te += __shfl_xor(te, m, 64);
                tp += __shfl_xor(tp, m, 64);
            }
            if (n15 == 0) {
                const int grow = bm * TILE + lr;
                atomicAdd(&tot[grow], te);
                atomicAdd(&pos[grow], tp);
            }
        }
    }

    if (!diag) {
        // column sums -> rows of tile bn; column fixed per lane (n15), 2 stages over q
        #pragma unroll
        for (int u = 0; u < 4; ++u) {
            float e = ce[u], p = cp[u];
            e += __shfl_xor(e, 16, 64);  p += __shfl_xor(p, 16, 64);
            e += __shfl_xor(e, 32, 64);  p += __shfl_xor(p, 32, 64);
            if (lane < 16) {
                const int grow = bn * TILE + wc * 64 + u * 16 + n15;
                atomicAdd(&tot[grow], e);
                atomicAdd(&pos[grow], p);
            }
        }
    }

    // ---- fused finalize: last block reduces loss ----
    __threadfence();          // release our atomics before counter bump
    __syncthreads();          // all waves of this block done
    if (tid == 0) lastflag = (atomicAdd(cnt, 1) == NBLK - 1);
    __syncthreads();
    if (lastflag) {
        __threadfence();      // acquire
        float s = 0.0f;
        for (int i = tid; i < N; i += 256) {
            const float tv = __hip_atomic_load(&tot[i], __ATOMIC_RELAXED, __HIP_MEMORY_SCOPE_AGENT);
            const float pv = __hip_atomic_load(&pos[i], __ATOMIC_RELAXED, __HIP_MEMORY_SCOPE_AGENT);
            s += __logf(tv + 1e-8f) - __logf(pv);
        }
        #pragma unroll
        for (int m = 32; m; m >>= 1) s += __shfl_xor(s, m, 64);
        if (lane == 0) red[wave] = s;
        __syncthreads();
        if (tid == 0) out[0] = red[0] + red[1] + red[2] + red[3];
    }
}

extern "C" void kernel_launch(void* const* d_in, const int* in_sizes, int n_in,
                              void* d_out, int out_size, void* d_ws, size_t ws_size,
                              hipStream_t stream) {
    const float* F  = (const float*)d_in[0];
    const int*   cl = (const int*)d_in[1];
    float* out = (float*)d_out;

    short* Fn2 = (short*)d_ws;                                   // 8 MB fragment-major
    float* tot = (float*)((char*)d_ws + (size_t)N * D * 2);      // 32 KB
    float* pos = tot + N;                                        // 32 KB
    int*   cnt = (int*)(pos + N);                                // 4 B done-counter

    cc_normalize<<<N / 4, 256, 0, stream>>>(F, Fn2, tot, cnt);
    cc_gemm<<<NBLK, 256, 0, stream>>>(Fn2, cl, tot, pos, cnt, out);
}